// Round 1
// baseline (107.611 us; speedup 1.0000x reference)
//
#include <hip/hip_runtime.h>

#define NB 16   // batch
#define TT 40   // max targets
#define BA 3    // anchors per scale
#define CC 20   // classes

__constant__ float cANCH[18] = {10,13, 16,30, 33,23, 30,61, 62,45,
                                59,119, 116,90, 156,198, 373,326};

__device__ __forceinline__ float sigmoidf_(float x){ return 1.f/(1.f+__expf(-x)); }

// One block = 256 cells of one (scale, image). Threads 0..39 first rebuild the
// per-target records in LDS (anchor argmax, encoding, match key), then every
// thread processes one cell: max-IoU vs valid targets (noobj), match scan
// (obj/cls/coords), block-reduce, one atomicAdd.
__global__ __launch_bounds__(256) void yolo_loss_33457795236259_kernel(
    const float* __restrict__ p0, const float* __restrict__ p1,
    const float* __restrict__ p2, const float* __restrict__ targets,
    const void* __restrict__ imgp, float* __restrict__ out)
{
  const int n  = blockIdx.y;
  const int bx = blockIdx.x;
  int s, g, cellbase;
  const float* pred;
  if (bx < 5)       { s = 0; g = 19; pred = p0; cellbase = bx * 256; }
  else if (bx < 22) { s = 1; g = 38; pred = p1; cellbase = (bx - 5) * 256; }
  else              { s = 2; g = 76; pred = p2; cellbase = (bx - 22) * 256; }

  __shared__ float stx1[TT], stx2[TT], sty1[TT], sty2[TT], sarea[TT];
  __shared__ float senc0[TT], senc1[TT], senc2[TT], senc3[TT], sscl[TT];
  __shared__ int   smkey[TT];
  __shared__ int   scount;
  __shared__ float swsum[4];

  // img_size: defensively decode int32 or float32 single-element array
  float img;
  { int v = *(const int*)imgp;
    img = (v >= 1 && v <= 1000000) ? (float)v : *(const float*)imgp; }

  const int tid = threadIdx.x;
  if (tid < TT) {
    const int t = tid;
    const float* tg = targets + (n * TT + t) * 5;
    float tcf = tg[0];
    float tx = tg[1], ty = tg[2], tw = tg[3], th = tg[4];
    // valid = cumprod(x != 0) -> prefix property
    bool valid = true;
    for (int u = 0; u <= t; ++u)
      if (targets[(n * TT + u) * 5 + 1] == 0.f) { valid = false; break; }
    stx1[t] = tx - tw * 0.5f; stx2[t] = tx + tw * 0.5f;
    sty1[t] = ty - th * 0.5f; sty2[t] = ty + th * 0.5f;
    sarea[t] = tw * th;
    sscl[t]  = 2.f - tw * th;
    // anchor argmax over all 9 anchors (centered boxes -> overlap = min of sizes)
    int k = 0; float best = -1.f;
    for (int a = 0; a < 9; ++a) {
      float aw = cANCH[2*a] / img, ah = cANCH[2*a+1] / img;
      float inter = fminf(aw, tw) * fminf(ah, th);
      float uni   = aw * ah + tw * th - inter;
      float iou   = inter / (uni + 1e-16f);
      if (iou > best) { best = iou; k = a; }   // strict: first max (jnp.argmax)
    }
    float gf = (float)g;
    int ii = (int)floorf(tx * gf); ii = ii < 0 ? 0 : (ii > g-1 ? g-1 : ii);
    int jj = (int)floorf(ty * gf); jj = jj < 0 ? 0 : (jj > g-1 ? g-1 : jj);
    bool m = valid && (k / BA == s);
    int kl = k % BA;
    int tc = (int)tcf;
    // key: col(7b) | row(7b)<<7 | local(2b)<<14 | tcls<<16 ; -1 = unmatched
    smkey[t] = m ? (ii | (jj << 7) | (kl << 14) | (tc << 16)) : -1;
    senc0[t] = tx * gf - (float)ii;
    senc1[t] = ty * gf - (float)jj;
    senc2[t] = __logf(fmaxf(tw, 1e-12f) * img / cANCH[2*k]);
    senc3[t] = __logf(fmaxf(th, 1e-12f) * img / cANCH[2*k+1]);
    if (t == 0) {
      int cnt = 0;
      while (cnt < TT && targets[(n * TT + cnt) * 5 + 1] != 0.f) cnt++;
      scount = cnt;
    }
  }
  __syncthreads();

  float partial = 0.f;
  const int gg = g * g;
  const int cell = cellbase + tid;
  if (cell < BA * gg) {
    int b = cell / gg;
    int rem = cell - b * gg;
    int i = rem / g;            // row (y)
    int j = rem - i * g;        // col (x)
    const float* pc = pred + ((size_t)(n * BA + b) * (CC + 5)) * gg + rem;
    float rx = pc[0];
    float ry = pc[(size_t)gg];
    float rw = pc[(size_t)2 * gg];
    float rh = pc[(size_t)3 * gg];
    float rconf = pc[(size_t)4 * gg];
    float sx = sigmoidf_(rx), sy = sigmoidf_(ry), conf = sigmoidf_(rconf);
    float aw = cANCH[2*(s*BA+b)] / img, ah = cANCH[2*(s*BA+b)+1] / img;
    float pw = __expf(rw) * aw, ph = __expf(rh) * ah;
    float gf = (float)g;
    float cx = (sx + (float)j) / gf, cy = (sy + (float)i) / gf;
    float px1 = cx - pw * 0.5f, px2 = cx + pw * 0.5f;
    float py1 = cy - ph * 0.5f, py2 = cy + ph * 0.5f;
    float areaP = pw * ph;
    float maxiou = -1.f;
    int win = -1; unsigned clsmask = 0u;
    int mykey = j | (i << 7) | (b << 14);
    int cnt = scount;
    for (int t = 0; t < cnt; ++t) {
      float iw = fminf(px2, stx2[t]) - fmaxf(px1, stx1[t]);
      float ih = fminf(py2, sty2[t]) - fmaxf(py1, sty1[t]);
      iw = fmaxf(iw, 0.f); ih = fmaxf(ih, 0.f);
      float inter = iw * ih;
      float iou = inter / (areaP + sarea[t] - inter + 1e-16f);
      maxiou = fmaxf(maxiou, iou);
      int mk = smkey[t];
      if ((mk & 0xFFFF) == mykey) { win = t; clsmask |= 1u << (mk >> 16); }
    }
    if (win >= 0) {
      // obj: conf, coords (winner = last scatter), cls (union one-hot)
      float d = conf - 1.f; partial += d * d;
      float scl = sscl[win];
      float d0 = (sx - senc0[win]) * scl;
      float d1 = (sy - senc1[win]) * scl;
      float d2 = (rw - senc2[win]) * scl;
      float d3 = (rh - senc3[win]) * scl;
      partial += d0*d0 + d1*d1 + d2*d2 + d3*d3;
      #pragma unroll
      for (int c = 0; c < CC; ++c) {
        float pcl = sigmoidf_(pc[(size_t)(5 + c) * gg]);
        float tv = ((clsmask >> c) & 1u) ? 1.f : 0.f;
        float dd = pcl - tv;
        partial += dd * dd;
      }
    } else if (maxiou <= 0.7f) {
      partial += conf * conf;
    }
  }

  // block reduction: wave64 shuffle tree, then 4 wave sums in LDS
  #pragma unroll
  for (int o = 32; o >= 1; o >>= 1) partial += __shfl_down(partial, o, 64);
  int lane = tid & 63, wid = tid >> 6;
  if (lane == 0) swsum[wid] = partial;
  __syncthreads();
  if (tid == 0) {
    atomicAdd(out, (swsum[0] + swsum[1] + swsum[2] + swsum[3]) * (1.f / (float)NB));
  }
}

extern "C" void kernel_launch(void* const* d_in, const int* in_sizes, int n_in,
                              void* d_out, int out_size, void* d_ws, size_t ws_size,
                              hipStream_t stream) {
  const float* p0 = (const float*)d_in[0];  // (16, 75, 19, 19)
  const float* p1 = (const float*)d_in[1];  // (16, 75, 38, 38)
  const float* p2 = (const float*)d_in[2];  // (16, 75, 76, 76)
  const float* tg = (const float*)d_in[3];  // (16, 40, 5)
  const void*  im = d_in[4];                // scalar img_size
  float* out = (float*)d_out;               // scalar f32

  // d_out is re-poisoned before every launch -> zero the accumulator first.
  hipMemsetAsync(out, 0, sizeof(float), stream);

  // 5 + 17 + 68 block-columns cover 3*19^2, 3*38^2, 3*76^2 cells.
  dim3 grid(90, NB);
  yolo_loss_33457795236259_kernel<<<grid, 256, 0, stream>>>(p0, p1, p2, tg, im, out);
}

// Round 2
// 102.084 us; speedup vs baseline: 1.0542x; 1.0542x over previous
//
#include <hip/hip_runtime.h>

#define NB 16   // batch
#define TT 40   // max targets
#define BA 3    // anchors per scale
#define CC 20   // classes
#define GX 90   // block-columns per image (5 + 17 + 68)

__constant__ float cANCH[18] = {10,13, 16,30, 33,23, 30,61, 62,45,
                                59,119, 116,90, 156,198, 373,326};

__device__ __forceinline__ float sigmoidf_(float x){ return 1.f/(1.f+__expf(-x)); }

// Kernel 1: one block = 256 cells of one (scale, image). Prep per-target
// records in LDS (packed for b128/b64 reads), per-cell max-IoU + match scan,
// block reduce, write one partial per block to d_ws (no atomics, no memset).
__global__ __launch_bounds__(256) void yolo_part_kernel(
    const float* __restrict__ p0, const float* __restrict__ p1,
    const float* __restrict__ p2, const float* __restrict__ targets,
    const void* __restrict__ imgp, float* __restrict__ partials)
{
  const int n  = blockIdx.y;
  const int bx = blockIdx.x;
  int s, g, cellbase;
  const float* pred;
  if (bx < 5)       { s = 0; g = 19; pred = p0; cellbase = bx * 256; }
  else if (bx < 22) { s = 1; g = 38; pred = p1; cellbase = (bx - 5) * 256; }
  else              { s = 2; g = 76; pred = p2; cellbase = (bx - 22) * 256; }

  __shared__ float4 sbox[TT];   // x1, x2, y1, y2
  __shared__ float2 sai[TT];    // area, key (int bits)
  __shared__ float4 sencv[TT];  // enc0..enc3
  __shared__ float  sscl[TT];
  __shared__ int    scount;
  __shared__ float  swsum[4];

  // img_size: defensively decode int32 or float32 single-element array
  float img;
  { int v = *(const int*)imgp;
    img = (v >= 1 && v <= 1000000) ? (float)v : *(const float*)imgp; }

  const int tid = threadIdx.x;
  if (tid == 0) {
    // valid = cumprod(x != 0) is a prefix -> just count leading nonzero-x
    int cnt = 0;
    while (cnt < TT && targets[(n * TT + cnt) * 5 + 1] != 0.f) cnt++;
    scount = cnt;
  }
  __syncthreads();
  if (tid < TT) {
    const int t = tid;
    const float* tg = targets + (n * TT + t) * 5;
    float tcf = tg[0];
    float tx = tg[1], ty = tg[2], tw = tg[3], th = tg[4];
    bool valid = t < scount;
    sbox[t] = make_float4(tx - tw * 0.5f, tx + tw * 0.5f,
                          ty - th * 0.5f, ty + th * 0.5f);
    sscl[t] = 2.f - tw * th;
    // anchor argmax over all 9 anchors (centered boxes -> overlap = min sizes)
    int k = 0; float best = -1.f;
    for (int a = 0; a < 9; ++a) {
      float aw = cANCH[2*a] / img, ah = cANCH[2*a+1] / img;
      float inter = fminf(aw, tw) * fminf(ah, th);
      float uni   = aw * ah + tw * th - inter;
      float iou   = inter / (uni + 1e-16f);
      if (iou > best) { best = iou; k = a; }   // first max (jnp.argmax)
    }
    float gf = (float)g;
    int ii = (int)floorf(tx * gf); ii = ii < 0 ? 0 : (ii > g-1 ? g-1 : ii);
    int jj = (int)floorf(ty * gf); jj = jj < 0 ? 0 : (jj > g-1 ? g-1 : jj);
    bool m = valid && (k / BA == s);
    int kl = k % BA;
    int tc = (int)tcf;
    // key: col(7b) | row(7b)<<7 | local(2b)<<14 | tcls<<16 ; -1 = unmatched
    int key = m ? (ii | (jj << 7) | (kl << 14) | (tc << 16)) : -1;
    sai[t] = make_float2(tw * th, __int_as_float(key));
    sencv[t] = make_float4(tx * gf - (float)ii, ty * gf - (float)jj,
                           __logf(fmaxf(tw, 1e-12f) * img / cANCH[2*k]),
                           __logf(fmaxf(th, 1e-12f) * img / cANCH[2*k+1]));
  }
  __syncthreads();

  float partial = 0.f;
  const int gg = g * g;
  const int cell = cellbase + tid;
  if (cell < BA * gg) {
    int b = cell / gg;
    int rem = cell - b * gg;
    int i = rem / g;            // row (y)
    int j = rem - i * g;        // col (x)
    const float* pc = pred + ((size_t)(n * BA + b) * (CC + 5)) * gg + rem;
    float rx = pc[0];
    float ry = pc[(size_t)gg];
    float rw = pc[(size_t)2 * gg];
    float rh = pc[(size_t)3 * gg];
    float rconf = pc[(size_t)4 * gg];
    float sx = sigmoidf_(rx), sy = sigmoidf_(ry), conf = sigmoidf_(rconf);
    float aw = cANCH[2*(s*BA+b)] / img, ah = cANCH[2*(s*BA+b)+1] / img;
    float pw = __expf(rw) * aw, ph = __expf(rh) * ah;
    float gf = (float)g;
    float cx = (sx + (float)j) / gf, cy = (sy + (float)i) / gf;
    float px1 = cx - pw * 0.5f, px2 = cx + pw * 0.5f;
    float py1 = cy - ph * 0.5f, py2 = cy + ph * 0.5f;
    float areaP = pw * ph;
    float maxiou = -1.f;
    int win = -1; unsigned clsmask = 0u;
    int mykey = j | (i << 7) | (b << 14);
    int cnt = scount;
    for (int t = 0; t < cnt; ++t) {
      float4 bb = sbox[t];           // one ds_read_b128
      float2 am = sai[t];            // one ds_read_b64
      float iw = fminf(px2, bb.y) - fmaxf(px1, bb.x);
      float ih = fminf(py2, bb.w) - fmaxf(py1, bb.z);
      iw = fmaxf(iw, 0.f); ih = fmaxf(ih, 0.f);
      float inter = iw * ih;
      float iou = inter / (areaP + am.x - inter + 1e-16f);
      maxiou = fmaxf(maxiou, iou);
      int mk = __float_as_int(am.y);
      if ((mk & 0xFFFF) == mykey) { win = t; clsmask |= 1u << (mk >> 16); }
    }
    if (win >= 0) {
      // obj: conf, coords (winner = last scatter), cls (union one-hot)
      float d = conf - 1.f; partial += d * d;
      float scl = sscl[win];
      float4 e = sencv[win];
      float d0 = (sx - e.x) * scl;
      float d1 = (sy - e.y) * scl;
      float d2 = (rw - e.z) * scl;
      float d3 = (rh - e.w) * scl;
      partial += d0*d0 + d1*d1 + d2*d2 + d3*d3;
      #pragma unroll
      for (int c = 0; c < CC; ++c) {
        float pcl = sigmoidf_(pc[(size_t)(5 + c) * gg]);
        float tv = ((clsmask >> c) & 1u) ? 1.f : 0.f;
        float dd = pcl - tv;
        partial += dd * dd;
      }
    } else if (maxiou <= 0.7f) {
      partial += conf * conf;
    }
  }

  // block reduction: wave64 shuffle tree, then 4 wave sums via LDS
  #pragma unroll
  for (int o = 32; o >= 1; o >>= 1) partial += __shfl_down(partial, o, 64);
  int lane = tid & 63, wid = tid >> 6;
  if (lane == 0) swsum[wid] = partial;
  __syncthreads();
  if (tid == 0)
    partials[n * GX + bx] = swsum[0] + swsum[1] + swsum[2] + swsum[3];
}

// Kernel 2: reduce the 1440 block partials, write the scalar loss.
__global__ __launch_bounds__(256) void yolo_reduce_kernel(
    const float* __restrict__ partials, float* __restrict__ out)
{
  const int tid = threadIdx.x;
  float v = 0.f;
  for (int idx = tid; idx < NB * GX; idx += 256) v += partials[idx];
  #pragma unroll
  for (int o = 32; o >= 1; o >>= 1) v += __shfl_down(v, o, 64);
  __shared__ float swsum[4];
  if ((tid & 63) == 0) swsum[tid >> 6] = v;
  __syncthreads();
  if (tid == 0)
    out[0] = (swsum[0] + swsum[1] + swsum[2] + swsum[3]) * (1.f / (float)NB);
}

extern "C" void kernel_launch(void* const* d_in, const int* in_sizes, int n_in,
                              void* d_out, int out_size, void* d_ws, size_t ws_size,
                              hipStream_t stream) {
  const float* p0 = (const float*)d_in[0];  // (16, 75, 19, 19)
  const float* p1 = (const float*)d_in[1];  // (16, 75, 38, 38)
  const float* p2 = (const float*)d_in[2];  // (16, 75, 76, 76)
  const float* tg = (const float*)d_in[3];  // (16, 40, 5)
  const void*  im = d_in[4];                // scalar img_size
  float* out = (float*)d_out;               // scalar f32
  float* partials = (float*)d_ws;           // 1440 floats of scratch

  dim3 grid(GX, NB);
  yolo_part_kernel<<<grid, 256, 0, stream>>>(p0, p1, p2, tg, im, partials);
  yolo_reduce_kernel<<<1, 256, 0, stream>>>(partials, out);
}